// Round 6
// baseline (377.071 us; speedup 1.0000x reference)
//
#include <hip/hip_runtime.h>
#include <math.h>

#define N_USERS 100000
#define N_ITEMS 200000
#define N_NODES 300000
#define EMB_DIM 64
#define N_EDGES 4000000
#define BATCH   8192
#define EMB_REG 2.5e-05f

#define BUCK_SH 9                       // 512 nodes per bucket
#define BN      512
#define NBUCK   586                     // ceil(300000/512)
#define BSLOT   7424                    // slots per bucket region (mean 6827 + 7 sigma)
#define EPB     8192                    // edges per block (partition kernel)
#define EPT     32                      // edges per thread
#define NBLK_A  489                     // ceil(N_EDGES/EPB)
#define NBLK_MARK (BATCH / 256)         // 32 mark blocks folded into kA
#define PACK_SH 19                      // t in bits[0:19), hrel in bits[19:28)
#define SCORE_BLOCKS (BATCH / 4)
#define SPMM_QBLK 1172                  // blocks per spmm1 quarter (x64 = 75,008 nodes)

typedef unsigned short u16;
typedef unsigned int   u32;
typedef unsigned char  u8;
typedef __attribute__((ext_vector_type(8))) u16 u16x8;
typedef __attribute__((ext_vector_type(2))) float f32x2;

__device__ __forceinline__ float bf2f(u16 x) {
    u32 u = ((u32)x) << 16;
    return __builtin_bit_cast(float, u);
}
__device__ __forceinline__ u16 f2bf(float f) {
    u32 u = __builtin_bit_cast(u32, f);
    return (u16)((u + 0x7FFFu + ((u >> 16) & 1u)) >> 16);
}

// ---------- phase A: partition edges into fixed bucket regions ----------
// LDS-staged, bucket-ordered scatter -> coalesced global flush.
// Tail blocks (blockIdx >= NBLK_A) do the scored-node marking and zero the
// fp8 dummy row of e0s8.
__global__ __launch_bounds__(256) void kA(const int* __restrict__ hh,
                                          const int* __restrict__ tt,
                                          int* __restrict__ bcur, int* __restrict__ gp,
                                          const int* __restrict__ users,
                                          const int* __restrict__ pos,
                                          const int* __restrict__ neg,
                                          u8* __restrict__ flags,
                                          u8* __restrict__ e0s8) {
    if (blockIdx.x >= NBLK_A) {        // ---- folded k_mark ----
        int i = (blockIdx.x - NBLK_A) * 256 + threadIdx.x;
        if (i < BATCH) {
            flags[users[i]] = 1;
            flags[N_USERS + pos[i]] = 1;
            flags[N_USERS + neg[i]] = 1;
        }
        if (blockIdx.x == NBLK_A && threadIdx.x < 16)   // zero dummy fp8 row (e0s8)
            ((int*)(e0s8 + (size_t)N_NODES * EMB_DIM))[threadIdx.x] = 0;
        return;
    }
    __shared__ int sh_cnt[NBUCK];
    __shared__ int sh_off[NBUCK];      // local exclusive offsets (block CSR)
    __shared__ int sh_base[NBUCK];     // global destination bases
    __shared__ int stage[EPB];         // bucket-ordered packed edges (32 kB)
    __shared__ u16 sbid[EPB];          // bucket id per staged slot (16 kB)
    int tid = threadIdx.x;
    for (int j = tid; j < NBUCK; j += 256) sh_cnt[j] = 0;
    __syncthreads();
    int cbase = blockIdx.x * EPB;
    int clen  = min(EPB, N_EDGES - cbase);
    int pk[EPT], bk[EPT];
    #pragma unroll
    for (int j = 0; j < EPT; ++j) {
        int i = j * 256 + tid;
        bk[j] = -1;
        if (i < clen) {
            int h = hh[cbase + i];
            int t = tt[cbase + i];
            int b = h >> BUCK_SH;
            bk[j] = b;
            pk[j] = ((h & (BN - 1)) << PACK_SH) | t;
            atomicAdd(&sh_cnt[b], 1);
        }
    }
    __syncthreads();
    if (tid < 64) {                    // exclusive scan over 586 bucket counts
        int lane = tid, carry = 0;
        for (int b0 = 0; b0 < NBUCK; b0 += 64) {
            int idx = b0 + lane;
            int v = (idx < NBUCK) ? sh_cnt[idx] : 0;
            int incl = v;
            #pragma unroll
            for (int d = 1; d < 64; d <<= 1) {
                int u = __shfl_up(incl, d, 64);
                if (lane >= d) incl += u;
            }
            if (idx < NBUCK) sh_off[idx] = carry + incl - v;
            carry += __shfl(incl, 63, 64);
        }
    }
    __syncthreads();
    for (int j = tid; j < NBUCK; j += 256) {
        int c = sh_cnt[j];
        sh_base[j] = j * BSLOT + (c ? atomicAdd(&bcur[j], c) : 0);
        sh_cnt[j] = 0;                 // reuse as local rank cursor
    }
    __syncthreads();
    #pragma unroll
    for (int j = 0; j < EPT; ++j) {
        if (bk[j] >= 0) {
            int r = atomicAdd(&sh_cnt[bk[j]], 1);
            int p = sh_off[bk[j]] + r;
            stage[p] = pk[j];
            sbid[p]  = (u16)bk[j];
        }
    }
    __syncthreads();
    for (int i = tid; i < clen; i += 256) {    // coalesced per-bucket runs
        int b = sbid[i];
        gp[sh_base[b] + i - sh_off[b]] = stage[i];
    }
}

// ---------- phase B: per-bucket exact CSR + sde[] + dinv[] + fp8 conversion ----------
__global__ __launch_bounds__(256) void kB(const int* __restrict__ bcur,
                                          int* __restrict__ gp,
                                          int2* __restrict__ sde, float* __restrict__ dinv,
                                          const float* __restrict__ uemb,
                                          const float* __restrict__ iemb,
                                          u8* __restrict__ e0s8) {
    __shared__ int   ncnt[BN];
    __shared__ int   noff[BN];
    __shared__ float sdv[BN];
    __shared__ int   slots[BSLOT];
    int b = blockIdx.x;
    int node0 = b << BUCK_SH;
    int nn = min(BN, N_NODES - node0);
    int base = b * BSLOT;
    int count = bcur[b];                         // relative cursor = exact count
    int tid = threadIdx.x;
    for (int j = tid; j < BN; j += 256) ncnt[j] = 0;
    __syncthreads();
    for (int i = tid; i < count; i += 256)
        atomicAdd(&ncnt[gp[base + i] >> PACK_SH], 1);
    __syncthreads();
    if (tid < 64) {                       // exclusive scan over 512 node counts
        int lane = tid, carry = 0;
        #pragma unroll
        for (int b0 = 0; b0 < BN; b0 += 64) {
            int idx = b0 + lane;
            int v = ncnt[idx];
            int incl = v;
            #pragma unroll
            for (int d = 1; d < 64; d <<= 1) {
                int u = __shfl_up(incl, d, 64);
                if (lane >= d) incl += u;
            }
            noff[idx] = carry + incl - v;
            carry += __shfl(incl, 63, 64);
        }
    }
    __syncthreads();
    for (int j = tid; j < nn; j += 256) {
        int c = ncnt[j];
        float dv = c > 0 ? rsqrtf((float)c) : 0.0f;
        sde[node0 + j]  = make_int2(base + noff[j], c);
        dinv[node0 + j] = dv;
        sdv[j] = dv;
    }
    __syncthreads();
    for (int j = tid; j < BN; j += 256) ncnt[j] = noff[j];   // ncnt = cursor
    __syncthreads();
    for (int i = tid; i < count; i += 256) {     // scatter t by node into LDS
        int p = gp[base + i];
        int r = atomicAdd(&ncnt[p >> PACK_SH], 1);
        slots[r] = p & ((1 << PACK_SH) - 1);
    }
    __syncthreads();
    for (int i = tid; i < count; i += 256)       // coalesced flush (aliases edges_t)
        gp[base + i] = slots[i];
    // fused: e0s8[v] = Q(dinv[v] * e0[v]) for this bucket's nodes
    for (int i = tid; i < nn * 8; i += 256) {
        int j = i >> 3;
        float sc = sdv[j];
        int gnode = node0 + j;
        size_t ebase = (size_t)gnode * EMB_DIM + (size_t)(i & 7) * 8;
        const size_t UELEMS = (size_t)N_USERS * EMB_DIM;
        const float* src = (ebase < UELEMS) ? uemb + ebase : iemb + (ebase - UELEMS);
        float4 a  = ((const float4*)src)[0];
        float4 c4 = ((const float4*)src)[1];
        u32 w0 = __builtin_amdgcn_cvt_pk_fp8_f32(sc * a.x,  sc * a.y,  0,  false);
        w0 = __builtin_amdgcn_cvt_pk_fp8_f32(sc * a.z,  sc * a.w,  w0, true);
        u32 w1 = __builtin_amdgcn_cvt_pk_fp8_f32(sc * c4.x, sc * c4.y, 0,  false);
        w1 = __builtin_amdgcn_cvt_pk_fp8_f32(sc * c4.z, sc * c4.w, w1, true);
        uint2 o; o.x = w0; o.y = w1;
        ((uint2*)e0s8)[(size_t)gnode * 8 + (i & 7)] = o;
    }
}

// ---------- layer-1 SpMM (fp8 pre-scaled rows): 16 nodes per wave ----------
// Split into four quarter-grids (node_base) for profiler visibility.
// Dead lanes at node==N_NODES write the zero dummy row of emb1s8 (dst8).
__global__ __launch_bounds__(256) void k_spmm1(const int2* __restrict__ sde,
                        const int* __restrict__ et,
                        const u8* __restrict__ src8,
                        const float* __restrict__ uemb, const float* __restrict__ iemb,
                        const u8* __restrict__ flags,
                        u16* __restrict__ dstb, u8* __restrict__ dst8,
                        int node_base) {
    int lane = threadIdx.x & 63;
    int g    = lane >> 2;          // node sub-index within wave (16 groups)
    int sl   = lane & 3;           // 16-B slot within the 64-B row
    int gb   = lane & 60;          // group base lane (for shfl)
    int node = node_base + blockIdx.x * 64 + ((threadIdx.x >> 6) << 4) + g;
    bool alive = node < N_NODES;
    int2 se = alive ? sde[node] : make_int2(0, 0);
    int s = se.x, ne = se.y;
    float dh = ne > 0 ? rsqrtf((float)ne) : 0.0f;   // == dinv[node], bit-identical
    float acc[16];
    #pragma unroll
    for (int k = 0; k < 16; ++k) acc[k] = 0.f;
    int nb = (ne + 3) & ~3;        // per-group bound -> divergent early exit
    for (int j0 = 0; j0 < nb; j0 += 4) {
        int idx = j0 + sl;
        int ets = (idx < ne) ? et[s + idx] : N_NODES;  // pad -> zero row
        #pragma unroll
        for (int jj = 0; jj < 4; ++jj) {
            int t = __shfl(ets, gb | jj, 64);          // src lane in own group
            uint4 d8 = ((const uint4*)(src8 + (size_t)t * EMB_DIM))[sl];
            f32x2 p;
            p = __builtin_amdgcn_cvt_pk_f32_fp8(d8.x, false); acc[0]  += p.x; acc[1]  += p.y;
            p = __builtin_amdgcn_cvt_pk_f32_fp8(d8.x, true);  acc[2]  += p.x; acc[3]  += p.y;
            p = __builtin_amdgcn_cvt_pk_f32_fp8(d8.y, false); acc[4]  += p.x; acc[5]  += p.y;
            p = __builtin_amdgcn_cvt_pk_f32_fp8(d8.y, true);  acc[6]  += p.x; acc[7]  += p.y;
            p = __builtin_amdgcn_cvt_pk_f32_fp8(d8.z, false); acc[8]  += p.x; acc[9]  += p.y;
            p = __builtin_amdgcn_cvt_pk_f32_fp8(d8.z, true);  acc[10] += p.x; acc[11] += p.y;
            p = __builtin_amdgcn_cvt_pk_f32_fp8(d8.w, false); acc[12] += p.x; acc[13] += p.y;
            p = __builtin_amdgcn_cvt_pk_f32_fp8(d8.w, true);  acc[14] += p.x; acc[15] += p.y;
        }
    }
    if (!alive) {
        if (node == N_NODES) {      // zero dummy row for k_score's padded loop
            uint4 z; z.x = 0; z.y = 0; z.z = 0; z.w = 0;
            ((uint4*)(dst8 + (size_t)N_NODES * EMB_DIM))[sl] = z;
        }
        return;
    }
    // epilogue: all 64 lanes active; wave covers 16 consecutive nodes
    const float* srow = (node < N_USERS)
        ? uemb + (size_t)node * EMB_DIM
        : iemb + (size_t)(node - N_USERS) * EMB_DIM;
    float4 a0 = ((const float4*)srow)[sl * 4 + 0];
    float4 a1 = ((const float4*)srow)[sl * 4 + 1];
    float4 a2 = ((const float4*)srow)[sl * 4 + 2];
    float4 a3 = ((const float4*)srow)[sl * 4 + 3];
    float v[16];
    v[0]  = dh * acc[0]  + a0.x; v[1]  = dh * acc[1]  + a0.y;
    v[2]  = dh * acc[2]  + a0.z; v[3]  = dh * acc[3]  + a0.w;
    v[4]  = dh * acc[4]  + a1.x; v[5]  = dh * acc[5]  + a1.y;
    v[6]  = dh * acc[6]  + a1.z; v[7]  = dh * acc[7]  + a1.w;
    v[8]  = dh * acc[8]  + a2.x; v[9]  = dh * acc[9]  + a2.y;
    v[10] = dh * acc[10] + a2.z; v[11] = dh * acc[11] + a2.w;
    v[12] = dh * acc[12] + a3.x; v[13] = dh * acc[13] + a3.y;
    v[14] = dh * acc[14] + a3.z; v[15] = dh * acc[15] + a3.w;
    uint4 ow;
    u32 w;
    w = __builtin_amdgcn_cvt_pk_fp8_f32(dh * v[0],  dh * v[1],  0, false);
    w = __builtin_amdgcn_cvt_pk_fp8_f32(dh * v[2],  dh * v[3],  w, true);  ow.x = w;
    w = __builtin_amdgcn_cvt_pk_fp8_f32(dh * v[4],  dh * v[5],  0, false);
    w = __builtin_amdgcn_cvt_pk_fp8_f32(dh * v[6],  dh * v[7],  w, true);  ow.y = w;
    w = __builtin_amdgcn_cvt_pk_fp8_f32(dh * v[8],  dh * v[9],  0, false);
    w = __builtin_amdgcn_cvt_pk_fp8_f32(dh * v[10], dh * v[11], w, true);  ow.z = w;
    w = __builtin_amdgcn_cvt_pk_fp8_f32(dh * v[12], dh * v[13], 0, false);
    w = __builtin_amdgcn_cvt_pk_fp8_f32(dh * v[14], dh * v[15], w, true);  ow.w = w;
    ((uint4*)(dst8 + (size_t)node * EMB_DIM))[sl] = ow;   // 1 kB/wave, coalesced
    if (flags[node]) {
        u16x8 o0, o1;
        o0.s0 = f2bf(v[0]);  o0.s1 = f2bf(v[1]);  o0.s2 = f2bf(v[2]);  o0.s3 = f2bf(v[3]);
        o0.s4 = f2bf(v[4]);  o0.s5 = f2bf(v[5]);  o0.s6 = f2bf(v[6]);  o0.s7 = f2bf(v[7]);
        o1.s0 = f2bf(v[8]);  o1.s1 = f2bf(v[9]);  o1.s2 = f2bf(v[10]); o1.s3 = f2bf(v[11]);
        o1.s4 = f2bf(v[12]); o1.s5 = f2bf(v[13]); o1.s6 = f2bf(v[14]); o1.s7 = f2bf(v[15]);
        ((u16x8*)(dstb + (size_t)node * EMB_DIM))[sl * 2]     = o0;
        ((u16x8*)(dstb + (size_t)node * EMB_DIM))[sl * 2 + 1] = o1;
    }
}

// ---------- scoring with fused layer-2 rows + fused final reduction ----------
// Interleaved x2-unrolled gathers (6 in flight). Last-done block performs the
// deterministic final reduction (fixed read order == old k_final).
__global__ void k_score(const int* __restrict__ users, const int* __restrict__ pos,
                        const int* __restrict__ neg,
                        const float* __restrict__ uemb, const float* __restrict__ iemb,
                        const u16* __restrict__ emb1b, const u8* __restrict__ emb1s8,
                        const int2* __restrict__ sde, const int* __restrict__ et,
                        const float* __restrict__ dinv,
                        float* __restrict__ pmf, float* __restrict__ psq,
                        int* __restrict__ cnt, float* __restrict__ out) {
    __shared__ float smf[4], ssq[4];
    __shared__ int swin;
    int gid = blockIdx.x * blockDim.x + threadIdx.x;
    int b = gid >> 6;
    int d = gid & 63;
    int w = threadIdx.x >> 6;
    int u  = users[b];
    int pi = pos[b];
    int ni = neg[b];
    int nodes[3];
    nodes[0] = u; nodes[1] = N_USERS + pi; nodes[2] = N_USERS + ni;
    float pre[3];
    pre[0] = uemb[(size_t)u * EMB_DIM + d];
    pre[1] = iemb[(size_t)pi * EMB_DIM + d];
    pre[2] = iemb[(size_t)ni * EMB_DIM + d];
    int s0[3], ne[3], ets[3], lim[3];
    float dv[3];
    #pragma unroll
    for (int k = 0; k < 3; ++k) {
        int v = nodes[k];
        int2 se = sde[v];
        s0[k] = se.x; ne[k] = se.y;
        dv[k] = dinv[v];
        ets[k] = (d < ne[k]) ? et[se.x + d] : 0;
        lim[k] = ne[k] < 64 ? ne[k] : 64;
    }
    int lmax = max(lim[0], max(lim[1], lim[2]));
    float ac[3] = {0.f, 0.f, 0.f};
    for (int j = 0; j < lmax; j += 2) {        // 6 gathers in flight
        u32 by[6];
        #pragma unroll
        for (int k = 0; k < 3; ++k) {
            int t0 = (j     < lim[k]) ? __shfl(ets[k], j,     64) : N_NODES;
            int t1 = (j + 1 < lim[k]) ? __shfl(ets[k], j + 1, 64) : N_NODES;
            by[k * 2]     = emb1s8[(size_t)t0 * EMB_DIM + d];
            by[k * 2 + 1] = emb1s8[(size_t)t1 * EMB_DIM + d];
        }
        #pragma unroll
        for (int k = 0; k < 3; ++k) {
            ac[k] += __builtin_amdgcn_cvt_f32_fp8(by[k * 2],     0);
            ac[k] += __builtin_amdgcn_cvt_f32_fp8(by[k * 2 + 1], 0);
        }
    }
    float a[3];
    #pragma unroll
    for (int k = 0; k < 3; ++k) {
        float acx = ac[k];
        for (int i = s0[k] + 64; i < s0[k] + ne[k]; ++i) {   // rare deg>64 tail
            int t = et[i];
            u32 byte = emb1s8[(size_t)t * EMB_DIM + d];
            acx += __builtin_amdgcn_cvt_f32_fp8(byte, 0);
        }
        a[k] = pre[k] + 2.0f * bf2f(emb1b[(size_t)nodes[k] * EMB_DIM + d]) + dv[k] * acx;
    }
    float ps = a[0] * a[1];
    float ns = a[0] * a[2];
    float sq = pre[0] * pre[0] + pre[1] * pre[1] + pre[2] * pre[2];
    #pragma unroll
    for (int off2 = 32; off2 > 0; off2 >>= 1) {
        ps += __shfl_down(ps, off2, 64);
        ns += __shfl_down(ns, off2, 64);
        sq += __shfl_down(sq, off2, 64);
    }
    if (d == 0) {
        float x  = ns - ps;
        smf[w] = fmaxf(x, 0.0f) + log1pf(expf(-fabsf(x)));
        ssq[w] = sq;
    }
    __syncthreads();
    if (threadIdx.x == 0) {
        pmf[blockIdx.x] = smf[0] + smf[1] + smf[2] + smf[3];
        psq[blockIdx.x] = ssq[0] + ssq[1] + ssq[2] + ssq[3];
        __threadfence();
        int old = __hip_atomic_fetch_add(cnt, 1, __ATOMIC_ACQ_REL,
                                         __HIP_MEMORY_SCOPE_AGENT);
        swin = (old == SCORE_BLOCKS - 1) ? 1 : 0;
    }
    __syncthreads();
    if (swin) {                         // deterministic final reduction
        __threadfence();
        int tid = threadIdx.x;
        float mf = 0.f, sq2 = 0.f;
        #pragma unroll
        for (int i = 0; i < SCORE_BLOCKS / 256; ++i) {
            u32 um = __hip_atomic_load((const u32*)&pmf[tid + i * 256],
                                       __ATOMIC_RELAXED, __HIP_MEMORY_SCOPE_AGENT);
            u32 us = __hip_atomic_load((const u32*)&psq[tid + i * 256],
                                       __ATOMIC_RELAXED, __HIP_MEMORY_SCOPE_AGENT);
            mf += __builtin_bit_cast(float, um);
            sq2 += __builtin_bit_cast(float, us);
        }
        #pragma unroll
        for (int off2 = 32; off2 > 0; off2 >>= 1) {
            mf += __shfl_down(mf, off2, 64);
            sq2 += __shfl_down(sq2, off2, 64);
        }
        if ((tid & 63) == 0) { smf[tid >> 6] = mf; ssq[tid >> 6] = sq2; }
        __syncthreads();
        if (tid == 0) {
            out[0] = (smf[0] + smf[1] + smf[2] + smf[3]) * (1.0f / BATCH);
            out[1] = EMB_REG * (ssq[0] + ssq[1] + ssq[2] + ssq[3]);
        }
    }
}

extern "C" void kernel_launch(void* const* d_in, const int* in_sizes, int n_in,
                              void* d_out, int out_size, void* d_ws, size_t ws_size,
                              hipStream_t stream) {
    const float* uemb  = (const float*)d_in[0];
    const float* iemb  = (const float*)d_in[1];
    const int*   all_h = (const int*)d_in[2];
    const int*   all_t = (const int*)d_in[3];
    const int*   users = (const int*)d_in[4];
    const int*   pos   = (const int*)d_in[5];
    const int*   neg   = (const int*)d_in[6];
    float* out = (float*)d_out;

    // workspace layout (int units); flags+bcur contiguous for single memset.
    // emb1s8 sized 300,001 rows (dummy zero row at index N_NODES) -- emb1b
    // starts 16 ints later to avoid overlap with the dummy row.
    int*   ws     = (int*)d_ws;
    float* dinv   = (float*)ws;                  // 300,032 floats
    int2*  sde    = (int2*)(ws + 300032);        // 600,064 ints
    u8*    flags  = (u8*)(ws + 900096);          // 75,008 ints (300,032 B)
    int*   bcur   = ws + 975104;                 // 1024 ints (zero-init, relative)
    float* pmf    = (float*)(ws + 976128);       // 2048
    float* psq    = (float*)(ws + 978176);       // 2048
    int*   gp     = ws + 980224;                 // 586*7424 = 4,350,464 ints
    u8*    e0s8   = (u8*)(ws + 5330688);         // 300,001 rows x 64 B (incl dummy)
    u8*    emb1s8 = (u8*)(ws + 10130944);        // 300,001 rows x 64 B (incl dummy)
    u16*   emb1b  = (u16*)(ws + 14930960);       // 9.6M ints (38.4 MB)
    int*   cnt    = bcur + 640;                  // inside zeroed bcur region

    // one memset covers flags (300,032 B) + bcur/cnt (4,096 B)
    hipMemsetAsync(flags, 0, 304128, stream);

    // partition (+ folded mark + e0s8 dummy-row zero)
    kA <<<NBLK_A + NBLK_MARK, 256, 0, stream>>>(all_h, all_t, bcur, gp,
                                                users, pos, neg, flags, e0s8);
    kB <<<NBUCK, 256, 0, stream>>>(bcur, gp, sde, dinv, uemb, iemb, e0s8);

    // layer 1 in four quarters (profiler visibility of hidden kernels)
    for (int q = 0; q < 4; ++q)
        k_spmm1<<<SPMM_QBLK, 256, 0, stream>>>(sde, gp, e0s8, uemb, iemb,
                                               flags, emb1b, emb1s8,
                                               q * SPMM_QBLK * 64);

    // scoring + fused final reduction
    k_score<<<SCORE_BLOCKS, 256, 0, stream>>>(users, pos, neg, uemb, iemb,
                                              emb1b, emb1s8, sde, gp, dinv,
                                              pmf, psq, cnt, out);
}

// Round 7
// 284.256 us; speedup vs baseline: 1.3265x; 1.3265x over previous
//
#include <hip/hip_runtime.h>
#include <math.h>

#define N_USERS 100000
#define N_ITEMS 200000
#define N_NODES 300000
#define EMB_DIM 64
#define N_EDGES 4000000
#define BATCH   8192
#define EMB_REG 2.5e-05f

#define BUCK_SH 9                       // 512 nodes per bucket
#define BN      512
#define NBUCK   586                     // ceil(300000/512)
#define BSLOT   7424                    // slots per bucket region (mean 6827 + 7 sigma)
#define EPB     8192                    // edges per block (partition kernel)
#define EPT     32                      // edges per thread
#define NBLK_A  489                     // ceil(N_EDGES/EPB)
#define NBLK_MARK (BATCH / 256)         // 32 mark blocks folded into kA
#define PACK_SH 19                      // t in bits[0:19), hrel in bits[19:28)
#define SCORE2_BLOCKS (BATCH / 16)      // 512 blocks, 16 batch elements each

typedef unsigned short u16;
typedef unsigned int   u32;
typedef unsigned char  u8;
typedef __attribute__((ext_vector_type(8))) u16 u16x8;
typedef __attribute__((ext_vector_type(2))) float f32x2;

__device__ __forceinline__ float bf2f(u16 x) {
    u32 u = ((u32)x) << 16;
    return __builtin_bit_cast(float, u);
}
__device__ __forceinline__ u16 f2bf(float f) {
    u32 u = __builtin_bit_cast(u32, f);
    return (u16)((u + 0x7FFFu + ((u >> 16) & 1u)) >> 16);
}

// ---------- phase A: partition edges into fixed bucket regions ----------
// LDS-staged, bucket-ordered scatter -> coalesced global flush.
// Tail blocks (blockIdx >= NBLK_A) do the scored-node marking and zero the
// fp8 dummy row of e0s8.
__global__ __launch_bounds__(256) void kA(const int* __restrict__ hh,
                                          const int* __restrict__ tt,
                                          int* __restrict__ bcur, int* __restrict__ gp,
                                          const int* __restrict__ users,
                                          const int* __restrict__ pos,
                                          const int* __restrict__ neg,
                                          u8* __restrict__ flags,
                                          u8* __restrict__ e0s8) {
    if (blockIdx.x >= NBLK_A) {        // ---- folded k_mark ----
        int i = (blockIdx.x - NBLK_A) * 256 + threadIdx.x;
        if (i < BATCH) {
            flags[users[i]] = 1;
            flags[N_USERS + pos[i]] = 1;
            flags[N_USERS + neg[i]] = 1;
        }
        if (blockIdx.x == NBLK_A && threadIdx.x < 16)   // zero dummy fp8 row (e0s8)
            ((int*)(e0s8 + (size_t)N_NODES * EMB_DIM))[threadIdx.x] = 0;
        return;
    }
    __shared__ int sh_cnt[NBUCK];
    __shared__ int sh_off[NBUCK];      // local exclusive offsets (block CSR)
    __shared__ int sh_base[NBUCK];     // global destination bases
    __shared__ int stage[EPB];         // bucket-ordered packed edges (32 kB)
    __shared__ u16 sbid[EPB];          // bucket id per staged slot (16 kB)
    int tid = threadIdx.x;
    for (int j = tid; j < NBUCK; j += 256) sh_cnt[j] = 0;
    __syncthreads();
    int cbase = blockIdx.x * EPB;
    int clen  = min(EPB, N_EDGES - cbase);
    int pk[EPT], bk[EPT];
    #pragma unroll
    for (int j = 0; j < EPT; ++j) {
        int i = j * 256 + tid;
        bk[j] = -1;
        if (i < clen) {
            int h = hh[cbase + i];
            int t = tt[cbase + i];
            int b = h >> BUCK_SH;
            bk[j] = b;
            pk[j] = ((h & (BN - 1)) << PACK_SH) | t;
            atomicAdd(&sh_cnt[b], 1);
        }
    }
    __syncthreads();
    if (tid < 64) {                    // exclusive scan over 586 bucket counts
        int lane = tid, carry = 0;
        for (int b0 = 0; b0 < NBUCK; b0 += 64) {
            int idx = b0 + lane;
            int v = (idx < NBUCK) ? sh_cnt[idx] : 0;
            int incl = v;
            #pragma unroll
            for (int d = 1; d < 64; d <<= 1) {
                int u = __shfl_up(incl, d, 64);
                if (lane >= d) incl += u;
            }
            if (idx < NBUCK) sh_off[idx] = carry + incl - v;
            carry += __shfl(incl, 63, 64);
        }
    }
    __syncthreads();
    for (int j = tid; j < NBUCK; j += 256) {
        int c = sh_cnt[j];
        sh_base[j] = j * BSLOT + (c ? atomicAdd(&bcur[j], c) : 0);
        sh_cnt[j] = 0;                 // reuse as local rank cursor
    }
    __syncthreads();
    #pragma unroll
    for (int j = 0; j < EPT; ++j) {
        if (bk[j] >= 0) {
            int r = atomicAdd(&sh_cnt[bk[j]], 1);
            int p = sh_off[bk[j]] + r;
            stage[p] = pk[j];
            sbid[p]  = (u16)bk[j];
        }
    }
    __syncthreads();
    for (int i = tid; i < clen; i += 256) {    // coalesced per-bucket runs
        int b = sbid[i];
        gp[sh_base[b] + i - sh_off[b]] = stage[i];
    }
}

// ---------- phase B: per-bucket exact CSR + sde[] + dinv[] + fp8 conversion ----------
__global__ __launch_bounds__(256) void kB(const int* __restrict__ bcur,
                                          int* __restrict__ gp,
                                          int2* __restrict__ sde, float* __restrict__ dinv,
                                          const float* __restrict__ uemb,
                                          const float* __restrict__ iemb,
                                          u8* __restrict__ e0s8) {
    __shared__ int   ncnt[BN];
    __shared__ int   noff[BN];
    __shared__ float sdv[BN];
    __shared__ int   slots[BSLOT];
    int b = blockIdx.x;
    int node0 = b << BUCK_SH;
    int nn = min(BN, N_NODES - node0);
    int base = b * BSLOT;
    int count = bcur[b];                         // relative cursor = exact count
    int tid = threadIdx.x;
    for (int j = tid; j < BN; j += 256) ncnt[j] = 0;
    __syncthreads();
    for (int i = tid; i < count; i += 256)
        atomicAdd(&ncnt[gp[base + i] >> PACK_SH], 1);
    __syncthreads();
    if (tid < 64) {                       // exclusive scan over 512 node counts
        int lane = tid, carry = 0;
        #pragma unroll
        for (int b0 = 0; b0 < BN; b0 += 64) {
            int idx = b0 + lane;
            int v = ncnt[idx];
            int incl = v;
            #pragma unroll
            for (int d = 1; d < 64; d <<= 1) {
                int u = __shfl_up(incl, d, 64);
                if (lane >= d) incl += u;
            }
            noff[idx] = carry + incl - v;
            carry += __shfl(incl, 63, 64);
        }
    }
    __syncthreads();
    for (int j = tid; j < nn; j += 256) {
        int c = ncnt[j];
        float dv = c > 0 ? rsqrtf((float)c) : 0.0f;
        sde[node0 + j]  = make_int2(base + noff[j], c);
        dinv[node0 + j] = dv;
        sdv[j] = dv;
    }
    __syncthreads();
    for (int j = tid; j < BN; j += 256) ncnt[j] = noff[j];   // ncnt = cursor
    __syncthreads();
    for (int i = tid; i < count; i += 256) {     // scatter t by node into LDS
        int p = gp[base + i];
        int r = atomicAdd(&ncnt[p >> PACK_SH], 1);
        slots[r] = p & ((1 << PACK_SH) - 1);
    }
    __syncthreads();
    for (int i = tid; i < count; i += 256)       // coalesced flush (aliases edges_t)
        gp[base + i] = slots[i];
    // fused: e0s8[v] = Q(dinv[v] * e0[v]) for this bucket's nodes
    for (int i = tid; i < nn * 8; i += 256) {
        int j = i >> 3;
        float sc = sdv[j];
        int gnode = node0 + j;
        size_t ebase = (size_t)gnode * EMB_DIM + (size_t)(i & 7) * 8;
        const size_t UELEMS = (size_t)N_USERS * EMB_DIM;
        const float* src = (ebase < UELEMS) ? uemb + ebase : iemb + (ebase - UELEMS);
        float4 a  = ((const float4*)src)[0];
        float4 c4 = ((const float4*)src)[1];
        u32 w0 = __builtin_amdgcn_cvt_pk_fp8_f32(sc * a.x,  sc * a.y,  0,  false);
        w0 = __builtin_amdgcn_cvt_pk_fp8_f32(sc * a.z,  sc * a.w,  w0, true);
        u32 w1 = __builtin_amdgcn_cvt_pk_fp8_f32(sc * c4.x, sc * c4.y, 0,  false);
        w1 = __builtin_amdgcn_cvt_pk_fp8_f32(sc * c4.z, sc * c4.w, w1, true);
        uint2 o; o.x = w0; o.y = w1;
        ((uint2*)e0s8)[(size_t)gnode * 8 + (i & 7)] = o;
    }
}

// ---------- layer-1 SpMM (fp8 pre-scaled rows): 16 nodes per wave ----------
// Dead lanes at node==N_NODES write the zero dummy row of emb1s8 (dst8),
// read by k_score2's padded gather.
__global__ __launch_bounds__(256) void k_spmm1(const int2* __restrict__ sde,
                        const int* __restrict__ et,
                        const u8* __restrict__ src8,
                        const float* __restrict__ uemb, const float* __restrict__ iemb,
                        const u8* __restrict__ flags,
                        u16* __restrict__ dstb, u8* __restrict__ dst8) {
    int lane = threadIdx.x & 63;
    int g    = lane >> 2;          // node sub-index within wave (16 groups)
    int sl   = lane & 3;           // 16-B slot within the 64-B row
    int gb   = lane & 60;          // group base lane (for shfl)
    int node = blockIdx.x * 64 + ((threadIdx.x >> 6) << 4) + g;
    bool alive = node < N_NODES;
    int2 se = alive ? sde[node] : make_int2(0, 0);
    int s = se.x, ne = se.y;
    float dh = ne > 0 ? rsqrtf((float)ne) : 0.0f;   // == dinv[node], bit-identical
    float acc[16];
    #pragma unroll
    for (int k = 0; k < 16; ++k) acc[k] = 0.f;
    int nb = (ne + 3) & ~3;        // per-group bound -> divergent early exit
    for (int j0 = 0; j0 < nb; j0 += 4) {
        int idx = j0 + sl;
        int ets = (idx < ne) ? et[s + idx] : N_NODES;  // pad -> zero row
        #pragma unroll
        for (int jj = 0; jj < 4; ++jj) {
            int t = __shfl(ets, gb | jj, 64);          // src lane in own group
            uint4 d8 = ((const uint4*)(src8 + (size_t)t * EMB_DIM))[sl];
            f32x2 p;
            p = __builtin_amdgcn_cvt_pk_f32_fp8(d8.x, false); acc[0]  += p.x; acc[1]  += p.y;
            p = __builtin_amdgcn_cvt_pk_f32_fp8(d8.x, true);  acc[2]  += p.x; acc[3]  += p.y;
            p = __builtin_amdgcn_cvt_pk_f32_fp8(d8.y, false); acc[4]  += p.x; acc[5]  += p.y;
            p = __builtin_amdgcn_cvt_pk_f32_fp8(d8.y, true);  acc[6]  += p.x; acc[7]  += p.y;
            p = __builtin_amdgcn_cvt_pk_f32_fp8(d8.z, false); acc[8]  += p.x; acc[9]  += p.y;
            p = __builtin_amdgcn_cvt_pk_f32_fp8(d8.z, true);  acc[10] += p.x; acc[11] += p.y;
            p = __builtin_amdgcn_cvt_pk_f32_fp8(d8.w, false); acc[12] += p.x; acc[13] += p.y;
            p = __builtin_amdgcn_cvt_pk_f32_fp8(d8.w, true);  acc[14] += p.x; acc[15] += p.y;
        }
    }
    if (!alive) {
        if (node == N_NODES) {      // zero dummy row for k_score2's padded gather
            uint4 z; z.x = 0; z.y = 0; z.z = 0; z.w = 0;
            ((uint4*)(dst8 + (size_t)N_NODES * EMB_DIM))[sl] = z;
        }
        return;
    }
    // epilogue: all 64 lanes active; wave covers 16 consecutive nodes
    const float* srow = (node < N_USERS)
        ? uemb + (size_t)node * EMB_DIM
        : iemb + (size_t)(node - N_USERS) * EMB_DIM;
    float4 a0 = ((const float4*)srow)[sl * 4 + 0];
    float4 a1 = ((const float4*)srow)[sl * 4 + 1];
    float4 a2 = ((const float4*)srow)[sl * 4 + 2];
    float4 a3 = ((const float4*)srow)[sl * 4 + 3];
    float v[16];
    v[0]  = dh * acc[0]  + a0.x; v[1]  = dh * acc[1]  + a0.y;
    v[2]  = dh * acc[2]  + a0.z; v[3]  = dh * acc[3]  + a0.w;
    v[4]  = dh * acc[4]  + a1.x; v[5]  = dh * acc[5]  + a1.y;
    v[6]  = dh * acc[6]  + a1.z; v[7]  = dh * acc[7]  + a1.w;
    v[8]  = dh * acc[8]  + a2.x; v[9]  = dh * acc[9]  + a2.y;
    v[10] = dh * acc[10] + a2.z; v[11] = dh * acc[11] + a2.w;
    v[12] = dh * acc[12] + a3.x; v[13] = dh * acc[13] + a3.y;
    v[14] = dh * acc[14] + a3.z; v[15] = dh * acc[15] + a3.w;
    uint4 ow;
    u32 w;
    w = __builtin_amdgcn_cvt_pk_fp8_f32(dh * v[0],  dh * v[1],  0, false);
    w = __builtin_amdgcn_cvt_pk_fp8_f32(dh * v[2],  dh * v[3],  w, true);  ow.x = w;
    w = __builtin_amdgcn_cvt_pk_fp8_f32(dh * v[4],  dh * v[5],  0, false);
    w = __builtin_amdgcn_cvt_pk_fp8_f32(dh * v[6],  dh * v[7],  w, true);  ow.y = w;
    w = __builtin_amdgcn_cvt_pk_fp8_f32(dh * v[8],  dh * v[9],  0, false);
    w = __builtin_amdgcn_cvt_pk_fp8_f32(dh * v[10], dh * v[11], w, true);  ow.z = w;
    w = __builtin_amdgcn_cvt_pk_fp8_f32(dh * v[12], dh * v[13], 0, false);
    w = __builtin_amdgcn_cvt_pk_fp8_f32(dh * v[14], dh * v[15], w, true);  ow.w = w;
    ((uint4*)(dst8 + (size_t)node * EMB_DIM))[sl] = ow;   // 1 kB/wave, coalesced
    if (flags[node]) {
        u16x8 o0, o1;
        o0.s0 = f2bf(v[0]);  o0.s1 = f2bf(v[1]);  o0.s2 = f2bf(v[2]);  o0.s3 = f2bf(v[3]);
        o0.s4 = f2bf(v[4]);  o0.s5 = f2bf(v[5]);  o0.s6 = f2bf(v[6]);  o0.s7 = f2bf(v[7]);
        o1.s0 = f2bf(v[8]);  o1.s1 = f2bf(v[9]);  o1.s2 = f2bf(v[10]); o1.s3 = f2bf(v[11]);
        o1.s4 = f2bf(v[12]); o1.s5 = f2bf(v[13]); o1.s6 = f2bf(v[14]); o1.s7 = f2bf(v[15]);
        ((u16x8*)(dstb + (size_t)node * EMB_DIM))[sl * 2]     = o0;
        ((u16x8*)(dstb + (size_t)node * EMB_DIM))[sl * 2 + 1] = o1;
    }
}

// ---------- scoring v2: spmm1-shaped gather + LDS handoff + dot phase ----------
// Block = 16 batch elements. Gather phase: wave k (k=0,1,2 -> u,pos,neg) handles
// the 16 segments of its kind; 4-lane groups keep 16 rows/load-instr in flight
// (same MLP shape as k_spmm1, which sustains 3.7 TB/s on this table vs the old
// k_score's 0.29 TB/s). Ascending add order + zero-row pads = same fp32 sums.
// Score phase: dots/softplus from LDS, no serial gather.
__global__ __launch_bounds__(256) void k_score2(
        const int* __restrict__ users, const int* __restrict__ pos,
        const int* __restrict__ neg,
        const float* __restrict__ uemb, const float* __restrict__ iemb,
        const u16* __restrict__ emb1b, const u8* __restrict__ emb1s8,
        const int2* __restrict__ sde, const int* __restrict__ et,
        const float* __restrict__ dinv,
        float* __restrict__ pmf, float* __restrict__ psq) {
    __shared__ float accL[3 * 16 * 64];      // [seg kind][b_loc][dim] = 12 kB
    __shared__ float smf[4], ssq[4];
    int tid  = threadIdx.x;
    int wv   = tid >> 6;           // wave 0..3; gather: wv==segment kind, wv3 idle
    int lane = tid & 63;
    int g    = lane >> 2;          // b_loc (16 groups = 16 batch elements)
    int sl   = lane & 3;           // 16-B slot (16 dims)
    int gb   = lane & 60;
    int B0   = blockIdx.x * 16;

    if (wv < 3) {
        int b = B0 + g;
        int node = (wv == 0) ? users[b]
                 : (wv == 1) ? (N_USERS + pos[b])
                             : (N_USERS + neg[b]);
        int2 se = sde[node];
        int s = se.x, ne = se.y;
        float acc[16];
        #pragma unroll
        for (int i = 0; i < 16; ++i) acc[i] = 0.f;
        int nb = (ne + 3) & ~3;    // per-group divergent bound
        for (int j0 = 0; j0 < nb; j0 += 4) {
            int idx = j0 + sl;
            int ets = (idx < ne) ? et[s + idx] : N_NODES;  // pad -> zero row
            #pragma unroll
            for (int jj = 0; jj < 4; ++jj) {
                int t = __shfl(ets, gb | jj, 64);
                uint4 d8 = ((const uint4*)(emb1s8 + (size_t)t * EMB_DIM))[sl];
                f32x2 p;
                p = __builtin_amdgcn_cvt_pk_f32_fp8(d8.x, false); acc[0]  += p.x; acc[1]  += p.y;
                p = __builtin_amdgcn_cvt_pk_f32_fp8(d8.x, true);  acc[2]  += p.x; acc[3]  += p.y;
                p = __builtin_amdgcn_cvt_pk_f32_fp8(d8.y, false); acc[4]  += p.x; acc[5]  += p.y;
                p = __builtin_amdgcn_cvt_pk_f32_fp8(d8.y, true);  acc[6]  += p.x; acc[7]  += p.y;
                p = __builtin_amdgcn_cvt_pk_f32_fp8(d8.z, false); acc[8]  += p.x; acc[9]  += p.y;
                p = __builtin_amdgcn_cvt_pk_f32_fp8(d8.z, true);  acc[10] += p.x; acc[11] += p.y;
                p = __builtin_amdgcn_cvt_pk_f32_fp8(d8.w, false); acc[12] += p.x; acc[13] += p.y;
                p = __builtin_amdgcn_cvt_pk_f32_fp8(d8.w, true);  acc[14] += p.x; acc[15] += p.y;
            }
        }
        float* dst = &accL[((wv * 16 + g) << 6) + (sl << 4)];
        ((float4*)dst)[0] = make_float4(acc[0],  acc[1],  acc[2],  acc[3]);
        ((float4*)dst)[1] = make_float4(acc[4],  acc[5],  acc[6],  acc[7]);
        ((float4*)dst)[2] = make_float4(acc[8],  acc[9],  acc[10], acc[11]);
        ((float4*)dst)[3] = make_float4(acc[12], acc[13], acc[14], acc[15]);
    }
    __syncthreads();
    // ---- score phase: wave wv handles batches wv*4 .. wv*4+3 ----
    float mfl = 0.f, sql = 0.f;
    int d = lane;
    #pragma unroll
    for (int q = 0; q < 4; ++q) {
        int bl = wv * 4 + q;
        int b  = B0 + bl;
        int u  = users[b];
        int pi = pos[b];
        int ni = neg[b];
        int n0 = u, n1 = N_USERS + pi, n2 = N_USERS + ni;
        float pre0 = uemb[(size_t)u  * EMB_DIM + d];
        float pre1 = iemb[(size_t)pi * EMB_DIM + d];
        float pre2 = iemb[(size_t)ni * EMB_DIM + d];
        float a0 = pre0 + 2.0f * bf2f(emb1b[(size_t)n0 * EMB_DIM + d])
                 + dinv[n0] * accL[((0 * 16 + bl) << 6) + d];
        float a1 = pre1 + 2.0f * bf2f(emb1b[(size_t)n1 * EMB_DIM + d])
                 + dinv[n1] * accL[((1 * 16 + bl) << 6) + d];
        float a2 = pre2 + 2.0f * bf2f(emb1b[(size_t)n2 * EMB_DIM + d])
                 + dinv[n2] * accL[((2 * 16 + bl) << 6) + d];
        float ps = a0 * a1;
        float ns = a0 * a2;
        float sq = pre0 * pre0 + pre1 * pre1 + pre2 * pre2;
        #pragma unroll
        for (int off2 = 32; off2 > 0; off2 >>= 1) {
            ps += __shfl_down(ps, off2, 64);
            ns += __shfl_down(ns, off2, 64);
            sq += __shfl_down(sq, off2, 64);
        }
        if (lane == 0) {
            float x = ns - ps;
            mfl += fmaxf(x, 0.0f) + log1pf(expf(-fabsf(x)));
            sql += sq;
        }
    }
    if (lane == 0) { smf[wv] = mfl; ssq[wv] = sql; }
    __syncthreads();
    if (tid == 0) {
        pmf[blockIdx.x] = smf[0] + smf[1] + smf[2] + smf[3];
        psq[blockIdx.x] = ssq[0] + ssq[1] + ssq[2] + ssq[3];
    }
}

// ---------- final reduction ----------
__global__ void k_final(const float* __restrict__ pmf, const float* __restrict__ psq,
                        float* __restrict__ out) {
    __shared__ float smf[4], ssq[4];
    int tid = threadIdx.x;
    float mf = 0.f, sq = 0.f;
    #pragma unroll
    for (int i = 0; i < SCORE2_BLOCKS / 256; ++i) {
        mf += pmf[tid + i * 256];
        sq += psq[tid + i * 256];
    }
    #pragma unroll
    for (int off2 = 32; off2 > 0; off2 >>= 1) {
        mf += __shfl_down(mf, off2, 64);
        sq += __shfl_down(sq, off2, 64);
    }
    if ((tid & 63) == 0) { smf[tid >> 6] = mf; ssq[tid >> 6] = sq; }
    __syncthreads();
    if (tid == 0) {
        out[0] = (smf[0] + smf[1] + smf[2] + smf[3]) * (1.0f / BATCH);
        out[1] = EMB_REG * (ssq[0] + ssq[1] + ssq[2] + ssq[3]);
    }
}

extern "C" void kernel_launch(void* const* d_in, const int* in_sizes, int n_in,
                              void* d_out, int out_size, void* d_ws, size_t ws_size,
                              hipStream_t stream) {
    const float* uemb  = (const float*)d_in[0];
    const float* iemb  = (const float*)d_in[1];
    const int*   all_h = (const int*)d_in[2];
    const int*   all_t = (const int*)d_in[3];
    const int*   users = (const int*)d_in[4];
    const int*   pos   = (const int*)d_in[5];
    const int*   neg   = (const int*)d_in[6];
    float* out = (float*)d_out;

    // workspace layout (int units); flags+bcur contiguous for single memset.
    // emb1s8 sized 300,001 rows (dummy zero row at index N_NODES) -- emb1b
    // starts 16 ints later to avoid overlap with the dummy row.
    int*   ws     = (int*)d_ws;
    float* dinv   = (float*)ws;                  // 300,032 floats
    int2*  sde    = (int2*)(ws + 300032);        // 600,064 ints
    u8*    flags  = (u8*)(ws + 900096);          // 75,008 ints (300,032 B)
    int*   bcur   = ws + 975104;                 // 1024 ints (zero-init, relative)
    float* pmf    = (float*)(ws + 976128);       // 2048
    float* psq    = (float*)(ws + 978176);       // 2048
    int*   gp     = ws + 980224;                 // 586*7424 = 4,350,464 ints
    u8*    e0s8   = (u8*)(ws + 5330688);         // 300,001 rows x 64 B (incl dummy)
    u8*    emb1s8 = (u8*)(ws + 10130944);        // 300,001 rows x 64 B (incl dummy)
    u16*   emb1b  = (u16*)(ws + 14930960);       // 9.6M ints (38.4 MB)

    // one memset covers flags (300,032 B) + bcur (4,096 B)
    hipMemsetAsync(flags, 0, 304128, stream);

    // partition (+ folded mark + e0s8 dummy-row zero)
    kA <<<NBLK_A + NBLK_MARK, 256, 0, stream>>>(all_h, all_t, bcur, gp,
                                                users, pos, neg, flags, e0s8);
    kB <<<NBUCK, 256, 0, stream>>>(bcur, gp, sde, dinv, uemb, iemb, e0s8);

    // layer 1: emb1 = A*Q(dinv*e0) + e0  (16 nodes/wave, 16 rows/load-instr)
    k_spmm1<<<(N_NODES + 63) / 64, 256, 0, stream>>>(sde, gp, e0s8, uemb, iemb,
                                                     flags, emb1b, emb1s8);

    // scoring: spmm1-shaped gather + LDS handoff + dot phase
    k_score2<<<SCORE2_BLOCKS, 256, 0, stream>>>(users, pos, neg, uemb, iemb,
                                                emb1b, emb1s8, sde, gp, dinv,
                                                pmf, psq);
    k_final<<<1, 256, 0, stream>>>(pmf, psq, out);
}

// Round 8
// 283.375 us; speedup vs baseline: 1.3306x; 1.0031x over previous
//
#include <hip/hip_runtime.h>
#include <math.h>

#define N_USERS 100000
#define N_ITEMS 200000
#define N_NODES 300000
#define EMB_DIM 64
#define N_EDGES 4000000
#define BATCH   8192
#define EMB_REG 2.5e-05f

#define BUCK_SH 8                       // 256 nodes per bucket (was 512)
#define BN      256
#define NBUCK   1172                    // ceil(300000/256)
#define BSLOT   3712                    // slots per bucket region (mean 3413 + 5.1 sigma)
#define EPB     8192                    // edges per block (partition kernel)
#define EPT     32                      // edges per thread
#define NBLK_A  489                     // ceil(N_EDGES/EPB)
#define NBLK_MARK (BATCH / 256)         // 32 mark blocks folded into kA
#define PACK_SH 19                      // t in bits[0:19), hrel in bits[19:27)
#define SCORE2_BLOCKS (BATCH / 16)      // 512 blocks, 16 batch elements each

typedef unsigned short u16;
typedef unsigned int   u32;
typedef unsigned char  u8;
typedef __attribute__((ext_vector_type(8))) u16 u16x8;
typedef __attribute__((ext_vector_type(2))) float f32x2;

__device__ __forceinline__ float bf2f(u16 x) {
    u32 u = ((u32)x) << 16;
    return __builtin_bit_cast(float, u);
}
__device__ __forceinline__ u16 f2bf(float f) {
    u32 u = __builtin_bit_cast(u32, f);
    return (u16)((u + 0x7FFFu + ((u >> 16) & 1u)) >> 16);
}

// ---------- phase A: partition edges into fixed bucket regions ----------
// LDS-staged, bucket-ordered scatter -> coalesced global flush.
// Tail blocks (blockIdx >= NBLK_A) do the scored-node marking and zero the
// fp8 dummy row of e0s8.
__global__ __launch_bounds__(256) void kA(const int* __restrict__ hh,
                                          const int* __restrict__ tt,
                                          int* __restrict__ bcur, int* __restrict__ gp,
                                          const int* __restrict__ users,
                                          const int* __restrict__ pos,
                                          const int* __restrict__ neg,
                                          u8* __restrict__ flags,
                                          u8* __restrict__ e0s8) {
    if (blockIdx.x >= NBLK_A) {        // ---- folded k_mark ----
        int i = (blockIdx.x - NBLK_A) * 256 + threadIdx.x;
        if (i < BATCH) {
            flags[users[i]] = 1;
            flags[N_USERS + pos[i]] = 1;
            flags[N_USERS + neg[i]] = 1;
        }
        if (blockIdx.x == NBLK_A && threadIdx.x < 16)   // zero dummy fp8 row (e0s8)
            ((int*)(e0s8 + (size_t)N_NODES * EMB_DIM))[threadIdx.x] = 0;
        return;
    }
    __shared__ int sh_cnt[NBUCK];      // 4.7 kB
    __shared__ int sh_off[NBUCK];      // local exclusive offsets (block CSR)
    __shared__ int sh_base[NBUCK];     // global destination bases
    __shared__ int stage[EPB];         // bucket-ordered packed edges (32 kB)
    __shared__ u16 sbid[EPB];          // bucket id per staged slot (16 kB)
    int tid = threadIdx.x;
    for (int j = tid; j < NBUCK; j += 256) sh_cnt[j] = 0;
    __syncthreads();
    int cbase = blockIdx.x * EPB;
    int clen  = min(EPB, N_EDGES - cbase);
    int pk[EPT], bk[EPT];
    #pragma unroll
    for (int j = 0; j < EPT; ++j) {
        int i = j * 256 + tid;
        bk[j] = -1;
        if (i < clen) {
            int h = hh[cbase + i];
            int t = tt[cbase + i];
            int b = h >> BUCK_SH;
            bk[j] = b;
            pk[j] = ((h & (BN - 1)) << PACK_SH) | t;
            atomicAdd(&sh_cnt[b], 1);
        }
    }
    __syncthreads();
    if (tid < 64) {                    // exclusive scan over 1172 bucket counts
        int lane = tid, carry = 0;
        for (int b0 = 0; b0 < NBUCK; b0 += 64) {
            int idx = b0 + lane;
            int v = (idx < NBUCK) ? sh_cnt[idx] : 0;
            int incl = v;
            #pragma unroll
            for (int d = 1; d < 64; d <<= 1) {
                int u = __shfl_up(incl, d, 64);
                if (lane >= d) incl += u;
            }
            if (idx < NBUCK) sh_off[idx] = carry + incl - v;
            carry += __shfl(incl, 63, 64);
        }
    }
    __syncthreads();
    for (int j = tid; j < NBUCK; j += 256) {
        int c = sh_cnt[j];
        sh_base[j] = j * BSLOT + (c ? atomicAdd(&bcur[j], c) : 0);
        sh_cnt[j] = 0;                 // reuse as local rank cursor
    }
    __syncthreads();
    #pragma unroll
    for (int j = 0; j < EPT; ++j) {
        if (bk[j] >= 0) {
            int r = atomicAdd(&sh_cnt[bk[j]], 1);
            int p = sh_off[bk[j]] + r;
            stage[p] = pk[j];
            sbid[p]  = (u16)bk[j];
        }
    }
    __syncthreads();
    for (int i = tid; i < clen; i += 256) {    // coalesced per-bucket runs
        int b = sbid[i];
        gp[sh_base[b] + i - sh_off[b]] = stage[i];
    }
}

// ---------- phase B: per-bucket exact CSR + sde[] + dinv[] ----------
// Halved buckets (256 nodes, ~3.4k edges) -> ~4.6 blocks/CU co-resident,
// half the per-block critical path. e0 conversion split out into k_conv.
__global__ __launch_bounds__(256) void kB(const int* __restrict__ bcur,
                                          int* __restrict__ gp,
                                          int2* __restrict__ sde, float* __restrict__ dinv) {
    __shared__ int   ncnt[BN];
    __shared__ int   noff[BN];
    __shared__ int   slots[BSLOT];
    int b = blockIdx.x;
    int node0 = b << BUCK_SH;
    int nn = min(BN, N_NODES - node0);
    int base = b * BSLOT;
    int count = bcur[b];                         // relative cursor = exact count
    int tid = threadIdx.x;
    for (int j = tid; j < BN; j += 256) ncnt[j] = 0;
    __syncthreads();
    for (int i = tid; i < count; i += 256)
        atomicAdd(&ncnt[gp[base + i] >> PACK_SH], 1);
    __syncthreads();
    if (tid < 64) {                       // exclusive scan over 256 node counts
        int lane = tid, carry = 0;
        #pragma unroll
        for (int b0 = 0; b0 < BN; b0 += 64) {
            int idx = b0 + lane;
            int v = ncnt[idx];
            int incl = v;
            #pragma unroll
            for (int d = 1; d < 64; d <<= 1) {
                int u = __shfl_up(incl, d, 64);
                if (lane >= d) incl += u;
            }
            noff[idx] = carry + incl - v;
            carry += __shfl(incl, 63, 64);
        }
    }
    __syncthreads();
    for (int j = tid; j < nn; j += 256) {
        int c = ncnt[j];
        float dv = c > 0 ? rsqrtf((float)c) : 0.0f;
        sde[node0 + j]  = make_int2(base + noff[j], c);
        dinv[node0 + j] = dv;
    }
    __syncthreads();
    for (int j = tid; j < BN; j += 256) ncnt[j] = noff[j];   // ncnt = cursor
    __syncthreads();
    for (int i = tid; i < count; i += 256) {     // scatter t by node into LDS
        int p = gp[base + i];
        int r = atomicAdd(&ncnt[p >> PACK_SH], 1);
        slots[r] = p & ((1 << PACK_SH) - 1);
    }
    __syncthreads();
    for (int i = tid; i < count; i += 256)       // coalesced flush (aliases edges_t)
        gp[base + i] = slots[i];
}

// ---------- e0 fp8 conversion: e0s8[v] = Q(dinv[v] * e0[v]) ----------
// Pure streaming kernel (was kB's serial epilogue): 76.8 MB read + 19.2 MB
// write, perfectly parallel. 9375 blocks x 256 = 8 threads per node row.
__global__ __launch_bounds__(256) void k_conv(const float* __restrict__ dinv,
                                              const float* __restrict__ uemb,
                                              const float* __restrict__ iemb,
                                              u8* __restrict__ e0s8) {
    int i = blockIdx.x * 256 + threadIdx.x;      // exact: 9375*256 = 2,400,000
    int node = i >> 3;
    float sc = dinv[node];
    size_t ebase = (size_t)node * EMB_DIM + (size_t)(i & 7) * 8;
    const size_t UELEMS = (size_t)N_USERS * EMB_DIM;
    const float* src = (ebase < UELEMS) ? uemb + ebase : iemb + (ebase - UELEMS);
    float4 a  = ((const float4*)src)[0];
    float4 c4 = ((const float4*)src)[1];
    u32 w0 = __builtin_amdgcn_cvt_pk_fp8_f32(sc * a.x,  sc * a.y,  0,  false);
    w0 = __builtin_amdgcn_cvt_pk_fp8_f32(sc * a.z,  sc * a.w,  w0, true);
    u32 w1 = __builtin_amdgcn_cvt_pk_fp8_f32(sc * c4.x, sc * c4.y, 0,  false);
    w1 = __builtin_amdgcn_cvt_pk_fp8_f32(sc * c4.z, sc * c4.w, w1, true);
    uint2 o; o.x = w0; o.y = w1;
    ((uint2*)e0s8)[(size_t)node * 8 + (i & 7)] = o;
}

// ---------- layer-1 SpMM (fp8 pre-scaled rows): 16 nodes per wave ----------
// Dead lanes at node==N_NODES write the zero dummy row of emb1s8 (dst8),
// read by k_score2's padded gather.
__global__ __launch_bounds__(256) void k_spmm1(const int2* __restrict__ sde,
                        const int* __restrict__ et,
                        const u8* __restrict__ src8,
                        const float* __restrict__ uemb, const float* __restrict__ iemb,
                        const u8* __restrict__ flags,
                        u16* __restrict__ dstb, u8* __restrict__ dst8) {
    int lane = threadIdx.x & 63;
    int g    = lane >> 2;          // node sub-index within wave (16 groups)
    int sl   = lane & 3;           // 16-B slot within the 64-B row
    int gb   = lane & 60;          // group base lane (for shfl)
    int node = blockIdx.x * 64 + ((threadIdx.x >> 6) << 4) + g;
    bool alive = node < N_NODES;
    int2 se = alive ? sde[node] : make_int2(0, 0);
    int s = se.x, ne = se.y;
    float dh = ne > 0 ? rsqrtf((float)ne) : 0.0f;   // == dinv[node], bit-identical
    float acc[16];
    #pragma unroll
    for (int k = 0; k < 16; ++k) acc[k] = 0.f;
    int nb = (ne + 3) & ~3;        // per-group bound -> divergent early exit
    for (int j0 = 0; j0 < nb; j0 += 4) {
        int idx = j0 + sl;
        int ets = (idx < ne) ? et[s + idx] : N_NODES;  // pad -> zero row
        #pragma unroll
        for (int jj = 0; jj < 4; ++jj) {
            int t = __shfl(ets, gb | jj, 64);          // src lane in own group
            uint4 d8 = ((const uint4*)(src8 + (size_t)t * EMB_DIM))[sl];
            f32x2 p;
            p = __builtin_amdgcn_cvt_pk_f32_fp8(d8.x, false); acc[0]  += p.x; acc[1]  += p.y;
            p = __builtin_amdgcn_cvt_pk_f32_fp8(d8.x, true);  acc[2]  += p.x; acc[3]  += p.y;
            p = __builtin_amdgcn_cvt_pk_f32_fp8(d8.y, false); acc[4]  += p.x; acc[5]  += p.y;
            p = __builtin_amdgcn_cvt_pk_f32_fp8(d8.y, true);  acc[6]  += p.x; acc[7]  += p.y;
            p = __builtin_amdgcn_cvt_pk_f32_fp8(d8.z, false); acc[8]  += p.x; acc[9]  += p.y;
            p = __builtin_amdgcn_cvt_pk_f32_fp8(d8.z, true);  acc[10] += p.x; acc[11] += p.y;
            p = __builtin_amdgcn_cvt_pk_f32_fp8(d8.w, false); acc[12] += p.x; acc[13] += p.y;
            p = __builtin_amdgcn_cvt_pk_f32_fp8(d8.w, true);  acc[14] += p.x; acc[15] += p.y;
        }
    }
    if (!alive) {
        if (node == N_NODES) {      // zero dummy row for k_score2's padded gather
            uint4 z; z.x = 0; z.y = 0; z.z = 0; z.w = 0;
            ((uint4*)(dst8 + (size_t)N_NODES * EMB_DIM))[sl] = z;
        }
        return;
    }
    // epilogue: all 64 lanes active; wave covers 16 consecutive nodes
    const float* srow = (node < N_USERS)
        ? uemb + (size_t)node * EMB_DIM
        : iemb + (size_t)(node - N_USERS) * EMB_DIM;
    float4 a0 = ((const float4*)srow)[sl * 4 + 0];
    float4 a1 = ((const float4*)srow)[sl * 4 + 1];
    float4 a2 = ((const float4*)srow)[sl * 4 + 2];
    float4 a3 = ((const float4*)srow)[sl * 4 + 3];
    float v[16];
    v[0]  = dh * acc[0]  + a0.x; v[1]  = dh * acc[1]  + a0.y;
    v[2]  = dh * acc[2]  + a0.z; v[3]  = dh * acc[3]  + a0.w;
    v[4]  = dh * acc[4]  + a1.x; v[5]  = dh * acc[5]  + a1.y;
    v[6]  = dh * acc[6]  + a1.z; v[7]  = dh * acc[7]  + a1.w;
    v[8]  = dh * acc[8]  + a2.x; v[9]  = dh * acc[9]  + a2.y;
    v[10] = dh * acc[10] + a2.z; v[11] = dh * acc[11] + a2.w;
    v[12] = dh * acc[12] + a3.x; v[13] = dh * acc[13] + a3.y;
    v[14] = dh * acc[14] + a3.z; v[15] = dh * acc[15] + a3.w;
    uint4 ow;
    u32 w;
    w = __builtin_amdgcn_cvt_pk_fp8_f32(dh * v[0],  dh * v[1],  0, false);
    w = __builtin_amdgcn_cvt_pk_fp8_f32(dh * v[2],  dh * v[3],  w, true);  ow.x = w;
    w = __builtin_amdgcn_cvt_pk_fp8_f32(dh * v[4],  dh * v[5],  0, false);
    w = __builtin_amdgcn_cvt_pk_fp8_f32(dh * v[6],  dh * v[7],  w, true);  ow.y = w;
    w = __builtin_amdgcn_cvt_pk_fp8_f32(dh * v[8],  dh * v[9],  0, false);
    w = __builtin_amdgcn_cvt_pk_fp8_f32(dh * v[10], dh * v[11], w, true);  ow.z = w;
    w = __builtin_amdgcn_cvt_pk_fp8_f32(dh * v[12], dh * v[13], 0, false);
    w = __builtin_amdgcn_cvt_pk_fp8_f32(dh * v[14], dh * v[15], w, true);  ow.w = w;
    ((uint4*)(dst8 + (size_t)node * EMB_DIM))[sl] = ow;   // 1 kB/wave, coalesced
    if (flags[node]) {
        u16x8 o0, o1;
        o0.s0 = f2bf(v[0]);  o0.s1 = f2bf(v[1]);  o0.s2 = f2bf(v[2]);  o0.s3 = f2bf(v[3]);
        o0.s4 = f2bf(v[4]);  o0.s5 = f2bf(v[5]);  o0.s6 = f2bf(v[6]);  o0.s7 = f2bf(v[7]);
        o1.s0 = f2bf(v[8]);  o1.s1 = f2bf(v[9]);  o1.s2 = f2bf(v[10]); o1.s3 = f2bf(v[11]);
        o1.s4 = f2bf(v[12]); o1.s5 = f2bf(v[13]); o1.s6 = f2bf(v[14]); o1.s7 = f2bf(v[15]);
        ((u16x8*)(dstb + (size_t)node * EMB_DIM))[sl * 2]     = o0;
        ((u16x8*)(dstb + (size_t)node * EMB_DIM))[sl * 2 + 1] = o1;
    }
}

// ---------- scoring v2: spmm1-shaped gather + LDS handoff + dot phase ----------
__global__ __launch_bounds__(256) void k_score2(
        const int* __restrict__ users, const int* __restrict__ pos,
        const int* __restrict__ neg,
        const float* __restrict__ uemb, const float* __restrict__ iemb,
        const u16* __restrict__ emb1b, const u8* __restrict__ emb1s8,
        const int2* __restrict__ sde, const int* __restrict__ et,
        const float* __restrict__ dinv,
        float* __restrict__ pmf, float* __restrict__ psq) {
    __shared__ float accL[3 * 16 * 64];      // [seg kind][b_loc][dim] = 12 kB
    __shared__ float smf[4], ssq[4];
    int tid  = threadIdx.x;
    int wv   = tid >> 6;           // wave 0..3; gather: wv==segment kind, wv3 idle
    int lane = tid & 63;
    int g    = lane >> 2;          // b_loc (16 groups = 16 batch elements)
    int sl   = lane & 3;           // 16-B slot (16 dims)
    int gb   = lane & 60;
    int B0   = blockIdx.x * 16;

    if (wv < 3) {
        int b = B0 + g;
        int node = (wv == 0) ? users[b]
                 : (wv == 1) ? (N_USERS + pos[b])
                             : (N_USERS + neg[b]);
        int2 se = sde[node];
        int s = se.x, ne = se.y;
        float acc[16];
        #pragma unroll
        for (int i = 0; i < 16; ++i) acc[i] = 0.f;
        int nb = (ne + 3) & ~3;    // per-group divergent bound
        for (int j0 = 0; j0 < nb; j0 += 4) {
            int idx = j0 + sl;
            int ets = (idx < ne) ? et[s + idx] : N_NODES;  // pad -> zero row
            #pragma unroll
            for (int jj = 0; jj < 4; ++jj) {
                int t = __shfl(ets, gb | jj, 64);
                uint4 d8 = ((const uint4*)(emb1s8 + (size_t)t * EMB_DIM))[sl];
                f32x2 p;
                p = __builtin_amdgcn_cvt_pk_f32_fp8(d8.x, false); acc[0]  += p.x; acc[1]  += p.y;
                p = __builtin_amdgcn_cvt_pk_f32_fp8(d8.x, true);  acc[2]  += p.x; acc[3]  += p.y;
                p = __builtin_amdgcn_cvt_pk_f32_fp8(d8.y, false); acc[4]  += p.x; acc[5]  += p.y;
                p = __builtin_amdgcn_cvt_pk_f32_fp8(d8.y, true);  acc[6]  += p.x; acc[7]  += p.y;
                p = __builtin_amdgcn_cvt_pk_f32_fp8(d8.z, false); acc[8]  += p.x; acc[9]  += p.y;
                p = __builtin_amdgcn_cvt_pk_f32_fp8(d8.z, true);  acc[10] += p.x; acc[11] += p.y;
                p = __builtin_amdgcn_cvt_pk_f32_fp8(d8.w, false); acc[12] += p.x; acc[13] += p.y;
                p = __builtin_amdgcn_cvt_pk_f32_fp8(d8.w, true);  acc[14] += p.x; acc[15] += p.y;
            }
        }
        float* dst = &accL[((wv * 16 + g) << 6) + (sl << 4)];
        ((float4*)dst)[0] = make_float4(acc[0],  acc[1],  acc[2],  acc[3]);
        ((float4*)dst)[1] = make_float4(acc[4],  acc[5],  acc[6],  acc[7]);
        ((float4*)dst)[2] = make_float4(acc[8],  acc[9],  acc[10], acc[11]);
        ((float4*)dst)[3] = make_float4(acc[12], acc[13], acc[14], acc[15]);
    }
    __syncthreads();
    // ---- score phase: wave wv handles batches wv*4 .. wv*4+3 ----
    float mfl = 0.f, sql = 0.f;
    int d = lane;
    #pragma unroll
    for (int q = 0; q < 4; ++q) {
        int bl = wv * 4 + q;
        int b  = B0 + bl;
        int u  = users[b];
        int pi = pos[b];
        int ni = neg[b];
        int n0 = u, n1 = N_USERS + pi, n2 = N_USERS + ni;
        float pre0 = uemb[(size_t)u  * EMB_DIM + d];
        float pre1 = iemb[(size_t)pi * EMB_DIM + d];
        float pre2 = iemb[(size_t)ni * EMB_DIM + d];
        float a0 = pre0 + 2.0f * bf2f(emb1b[(size_t)n0 * EMB_DIM + d])
                 + dinv[n0] * accL[((0 * 16 + bl) << 6) + d];
        float a1 = pre1 + 2.0f * bf2f(emb1b[(size_t)n1 * EMB_DIM + d])
                 + dinv[n1] * accL[((1 * 16 + bl) << 6) + d];
        float a2 = pre2 + 2.0f * bf2f(emb1b[(size_t)n2 * EMB_DIM + d])
                 + dinv[n2] * accL[((2 * 16 + bl) << 6) + d];
        float ps = a0 * a1;
        float ns = a0 * a2;
        float sq = pre0 * pre0 + pre1 * pre1 + pre2 * pre2;
        #pragma unroll
        for (int off2 = 32; off2 > 0; off2 >>= 1) {
            ps += __shfl_down(ps, off2, 64);
            ns += __shfl_down(ns, off2, 64);
            sq += __shfl_down(sq, off2, 64);
        }
        if (lane == 0) {
            float x = ns - ps;
            mfl += fmaxf(x, 0.0f) + log1pf(expf(-fabsf(x)));
            sql += sq;
        }
    }
    if (lane == 0) { smf[wv] = mfl; ssq[wv] = sql; }
    __syncthreads();
    if (tid == 0) {
        pmf[blockIdx.x] = smf[0] + smf[1] + smf[2] + smf[3];
        psq[blockIdx.x] = ssq[0] + ssq[1] + ssq[2] + ssq[3];
    }
}

// ---------- final reduction ----------
__global__ void k_final(const float* __restrict__ pmf, const float* __restrict__ psq,
                        float* __restrict__ out) {
    __shared__ float smf[4], ssq[4];
    int tid = threadIdx.x;
    float mf = 0.f, sq = 0.f;
    #pragma unroll
    for (int i = 0; i < SCORE2_BLOCKS / 256; ++i) {
        mf += pmf[tid + i * 256];
        sq += psq[tid + i * 256];
    }
    #pragma unroll
    for (int off2 = 32; off2 > 0; off2 >>= 1) {
        mf += __shfl_down(mf, off2, 64);
        sq += __shfl_down(sq, off2, 64);
    }
    if ((tid & 63) == 0) { smf[tid >> 6] = mf; ssq[tid >> 6] = sq; }
    __syncthreads();
    if (tid == 0) {
        out[0] = (smf[0] + smf[1] + smf[2] + smf[3]) * (1.0f / BATCH);
        out[1] = EMB_REG * (ssq[0] + ssq[1] + ssq[2] + ssq[3]);
    }
}

extern "C" void kernel_launch(void* const* d_in, const int* in_sizes, int n_in,
                              void* d_out, int out_size, void* d_ws, size_t ws_size,
                              hipStream_t stream) {
    const float* uemb  = (const float*)d_in[0];
    const float* iemb  = (const float*)d_in[1];
    const int*   all_h = (const int*)d_in[2];
    const int*   all_t = (const int*)d_in[3];
    const int*   users = (const int*)d_in[4];
    const int*   pos   = (const int*)d_in[5];
    const int*   neg   = (const int*)d_in[6];
    float* out = (float*)d_out;

    // workspace layout (int units); flags+bcur contiguous for single memset.
    // bcur now 1172 ints (padded to 1280); pmf/psq shrunk to true 512 size.
    // gp region byte-identical to before (1172*3712 == 586*7424).
    int*   ws     = (int*)d_ws;
    float* dinv   = (float*)ws;                  // 300,032 floats
    int2*  sde    = (int2*)(ws + 300032);        // 600,064 ints
    u8*    flags  = (u8*)(ws + 900096);          // 75,008 ints (300,032 B)
    int*   bcur   = ws + 975104;                 // 1280 ints (zero-init, relative)
    float* pmf    = (float*)(ws + 976384);       // 512
    float* psq    = (float*)(ws + 976896);       // 512
    int*   gp     = ws + 980224;                 // 1172*3712 = 4,350,464 ints
    u8*    e0s8   = (u8*)(ws + 5330688);         // 300,001 rows x 64 B (incl dummy)
    u8*    emb1s8 = (u8*)(ws + 10130944);        // 300,001 rows x 64 B (incl dummy)
    u16*   emb1b  = (u16*)(ws + 14930960);       // 9.6M ints (38.4 MB)

    // one memset covers flags (300,032 B) + bcur (5,120 B)
    hipMemsetAsync(flags, 0, 305152, stream);

    // partition (+ folded mark + e0s8 dummy-row zero)
    kA <<<NBLK_A + NBLK_MARK, 256, 0, stream>>>(all_h, all_t, bcur, gp,
                                                users, pos, neg, flags, e0s8);
    kB <<<NBUCK, 256, 0, stream>>>(bcur, gp, sde, dinv);

    // e0 fp8 conversion (streaming, was kB's serial epilogue)
    k_conv<<<9375, 256, 0, stream>>>(dinv, uemb, iemb, e0s8);

    // layer 1: emb1 = A*Q(dinv*e0) + e0  (16 nodes/wave, 16 rows/load-instr)
    k_spmm1<<<(N_NODES + 63) / 64, 256, 0, stream>>>(sde, gp, e0s8, uemb, iemb,
                                                     flags, emb1b, emb1s8);

    // scoring: spmm1-shaped gather + LDS handoff + dot phase
    k_score2<<<SCORE2_BLOCKS, 256, 0, stream>>>(users, pos, neg, uemb, iemb,
                                                emb1b, emb1s8, sde, gp, dinv,
                                                pmf, psq);
    k_final<<<1, 256, 0, stream>>>(pmf, psq, out);
}